// Round 6
// baseline (234.744 us; speedup 1.0000x reference)
//
#include <hip/hip_runtime.h>
#include <hip/hip_bf16.h>
#include <math.h>

typedef __bf16 bf16_t;
typedef __bf16 bf16x8 __attribute__((ext_vector_type(8)));
typedef float floatx4 __attribute__((ext_vector_type(4)));
typedef unsigned int uintx4 __attribute__((ext_vector_type(4)));

#define S_LEN 4096
#define DMODEL 1024
#define NH 16
#define DK 64
#define WELEM (DMODEL * DMODEL)
// 0.125 (1/sqrt(dk)) * log2(e): folded into RoPE's Q output (r13-validated)
#define SCALE_LOG2E 0.1803368801111204f

// qkv GEMM tile: 128x128, BK=64, pitch 72 (bank stride 36 -> worst 2-way, free)
#define QBM 128
#define QBN 128
#define QBK 64
#define QPITCH 72
// gemm_out tile (r10-validated): 128x64, BK=32, pitch 40
#define BM 128
#define BN 64
#define BK 32
#define APITCH 40

static __device__ __forceinline__ floatx4 mfma16(bf16x8 a, bf16x8 b, floatx4 c) {
  return __builtin_amdgcn_mfma_f32_16x16x32_bf16(a, b, c, 0, 0, 0);
}

// Raw barrier with lgkm-only wait: NO vmcnt drain (prefetch loads stay in
// flight across it — T3/T4). sched_barrier(0) pins scheduling on both sides.
static __device__ __forceinline__ void barrier_lgkm() {
  __builtin_amdgcn_sched_barrier(0);
  __asm__ volatile("s_waitcnt lgkmcnt(0)" ::: "memory");
  __builtin_amdgcn_s_barrier();
  __builtin_amdgcn_sched_barrier(0);
}

// bf16 pair pack (truncation — same rounding as the validated >>16 path):
// low half = a, high half = b.
static __device__ __forceinline__ unsigned int packbf(float a, float b) {
  return (__float_as_uint(a) >> 16) | (__float_as_uint(b) & 0xffff0000u);
}

// Paired cross-quad word exchanges (gfx950 permlane*_swap).
// swap32: a@{q2,q3} <-> b@{q0,q1}.  swap16: a@q1<->b@q0, a@q3<->b@q2.
static __device__ __forceinline__ void swap32(unsigned int& a, unsigned int& b) {
  auto r = __builtin_amdgcn_permlane32_swap(a, b, false, false);
  a = r[0]; b = r[1];
}
static __device__ __forceinline__ void swap16(unsigned int& a, unsigned int& b) {
  auto r = __builtin_amdgcn_permlane16_swap(a, b, false, false);
  a = r[0]; b = r[1];
}

// Per-tile chunk compute (r21-validated path, parameterized): swapped QK
// (lane (lr,quad) holds S[q=Q0+lr][kv=kvb+f*16+quad*4+r]), exp2, causal mask,
// lane-local lsum, bf16 pack + 4x4 cross-quad permlane transpose -> PV A-frags.
#define QK_SOFTMAX(QF0, QF1, LSUM, PF0, PF1, Q0, MASKED)                     \
  {                                                                          \
    floatx4 s_[4];                                                           \
    __builtin_amdgcn_s_setprio(1);                                           \
    _Pragma("unroll")                                                        \
    for (int f_ = 0; f_ < 4; ++f_) {                                         \
      floatx4 z_ = {0.f, 0.f, 0.f, 0.f};                                     \
      z_ = mfma16(kf[f_][0], QF0, z_);                                       \
      s_[f_] = mfma16(kf[f_][1], QF1, z_);                                   \
    }                                                                        \
    __builtin_amdgcn_s_setprio(0);                                           \
    unsigned int w_[4][2];                                                   \
    _Pragma("unroll")                                                        \
    for (int f_ = 0; f_ < 4; ++f_) {                                         \
      float pe_[4];                                                          \
      _Pragma("unroll")                                                      \
      for (int r_ = 0; r_ < 4; ++r_) {                                       \
        float v_ = __builtin_amdgcn_exp2f(s_[f_][r_]);                       \
        if (MASKED) {                                                        \
          int kv_ = kvb + f_ * 16 + quad * 4 + r_;                           \
          v_ = (kv_ <= (Q0) + lr) ? v_ : 0.f;                                \
        }                                                                    \
        LSUM += v_;                                                          \
        pe_[r_] = v_;                                                        \
      }                                                                      \
      w_[f_][0] = packbf(pe_[0], pe_[1]);                                    \
      w_[f_][1] = packbf(pe_[2], pe_[3]);                                    \
    }                                                                        \
    swap32(w_[0][0], w_[1][0]); swap16(w_[0][0], w_[1][0]);                  \
    swap32(w_[0][1], w_[1][1]); swap16(w_[0][1], w_[1][1]);                  \
    swap32(w_[2][0], w_[3][0]); swap16(w_[2][0], w_[3][0]);                  \
    swap32(w_[2][1], w_[3][1]); swap16(w_[2][1], w_[3][1]);                  \
    uintx4 u0_ = {w_[0][0], w_[0][1], w_[1][0], w_[1][1]};                   \
    uintx4 u1_ = {w_[2][0], w_[2][1], w_[3][0], w_[3][1]};                   \
    __builtin_memcpy(&PF0, &u0_, 16);                                        \
    __builtin_memcpy(&PF1, &u1_, 16);                                        \
  }

// fp32 -> bf16 elementwise convert (n multiple of 8).
__global__ __launch_bounds__(256) void cvt_f32_bf16(const float* __restrict__ src,
                                                    bf16_t* __restrict__ dst, int n) {
  int i = (blockIdx.x * blockDim.x + threadIdx.x) * 8;
  if (i >= n) return;
  float4 a = *(const float4*)(src + i);
  float4 b = *(const float4*)(src + i + 4);
  bf16x8 v;
  v[0] = (bf16_t)a.x; v[1] = (bf16_t)a.y; v[2] = (bf16_t)a.z; v[3] = (bf16_t)a.w;
  v[4] = (bf16_t)b.x; v[5] = (bf16_t)b.y; v[6] = (bf16_t)b.z; v[7] = (bf16_t)b.w;
  *(bf16x8*)(dst + i) = v;
}

// Convert Wq/Wk/Wv (fp32, 1M elems each) -> bf16 at dst[sel*WELEM].
__global__ __launch_bounds__(256) void wcvt3(const float* __restrict__ Wq,
                                             const float* __restrict__ Wk,
                                             const float* __restrict__ Wv,
                                             bf16_t* __restrict__ dst) {
  const int sel = blockIdx.y;
  const float* src = (sel == 0) ? Wq : ((sel == 1) ? Wk : Wv);
  int i = (blockIdx.x * blockDim.x + threadIdx.x) * 8;
  float4 a = *(const float4*)(src + i);
  float4 b = *(const float4*)(src + i + 4);
  bf16x8 v;
  v[0] = (bf16_t)a.x; v[1] = (bf16_t)a.y; v[2] = (bf16_t)a.z; v[3] = (bf16_t)a.w;
  v[4] = (bf16_t)b.x; v[5] = (bf16_t)b.y; v[6] = (bf16_t)b.z; v[7] = (bf16_t)b.w;
  *(bf16x8*)(dst + (size_t)sel * WELEM + i) = v;
}

// FUSED QKV GEMM, all-bf16: 128x128 tile, BK=64. Weights pre-converted (WB =
// [WqB|WkB|WvB] in d_out scratch). blockIdx.x: sel = x>>3, ntile = x&7.
// 4 waves (2x2), wave tile 64x64 (16 acc frags). Register-prefetch K-loop.
__global__ __launch_bounds__(256) void qkv_gemm(const bf16_t* __restrict__ A,
                                                const bf16_t* __restrict__ WB,
                                                bf16_t* __restrict__ Qo,
                                                bf16_t* __restrict__ Ko,
                                                bf16_t* __restrict__ Vo) {
  __shared__ __align__(16) bf16_t As[QBM * QPITCH];  // 18 KB
  __shared__ __align__(16) bf16_t Bs[QBN * QPITCH];  // 18 KB

  const int tid  = threadIdx.x;
  const int wid  = tid >> 6;
  const int lane = tid & 63;
  const int lr   = lane & 15;
  const int quad = lane >> 4;
  const int wm = wid >> 1, wn = wid & 1;
  const int sel = blockIdx.x >> 3;              // 0=Q, 1=K, 2=V
  const int n0  = (blockIdx.x & 7) * QBN;
  const int m0  = blockIdx.y * QBM;
  const bf16_t* Bsrc = WB + (size_t)sel * WELEM;

  // Staging: thread t -> row t>>1, k-offset (t&1)*32 (64 B = 4x bf16x8)
  const int sr = tid >> 1, sk = (tid & 1) * 32;
  const bf16_t* ag = A    + (size_t)(m0 + sr) * DMODEL + sk;
  const bf16_t* bg = Bsrc + (size_t)(n0 + sr) * DMODEL + sk;

  floatx4 acc[4][4];
#pragma unroll
  for (int i = 0; i < 4; ++i)
#pragma unroll
    for (int j = 0; j < 4; ++j) acc[i][j] = floatx4{0.f, 0.f, 0.f, 0.f};

  bf16x8 pa[4], pb[4];
#pragma unroll
  for (int u = 0; u < 4; ++u) {
    pa[u] = *(const bf16x8*)(ag + u * 8);
    pb[u] = *(const bf16x8*)(bg + u * 8);
  }

  for (int kb = 0; kb < DMODEL; kb += QBK) {
    __syncthreads();
#pragma unroll
    for (int u = 0; u < 4; ++u) {
      *(bf16x8*)(As + sr * QPITCH + sk + u * 8) = pa[u];
      *(bf16x8*)(Bs + sr * QPITCH + sk + u * 8) = pb[u];
    }
    __syncthreads();

    if (kb + QBK < DMODEL) {
#pragma unroll
      for (int u = 0; u < 4; ++u) {
        pa[u] = *(const bf16x8*)(ag + kb + QBK + u * 8);
        pb[u] = *(const bf16x8*)(bg + kb + QBK + u * 8);
      }
    }

#pragma unroll
    for (int s = 0; s < 2; ++s) {
      bf16x8 af[4], bfr[4];
#pragma unroll
      for (int i = 0; i < 4; ++i)
        af[i] = *(const bf16x8*)(As + (wm * 64 + i * 16 + lr) * QPITCH + s * 32 + quad * 8);
#pragma unroll
      for (int j = 0; j < 4; ++j)
        bfr[j] = *(const bf16x8*)(Bs + (wn * 64 + j * 16 + lr) * QPITCH + s * 32 + quad * 8);
#pragma unroll
      for (int i = 0; i < 4; ++i)
#pragma unroll
        for (int j = 0; j < 4; ++j)
          acc[i][j] = mfma16(af[i], bfr[j], acc[i][j]);
    }
  }

  bf16_t* Cn = (sel == 0) ? Qo : Ko;
#pragma unroll
  for (int i = 0; i < 4; ++i)
#pragma unroll
    for (int j = 0; j < 4; ++j)
#pragma unroll
      for (int r = 0; r < 4; ++r) {
        int row = m0 + wm * 64 + i * 16 + quad * 4 + r;
        int col = n0 + wn * 64 + j * 16 + lr;
        bf16_t v = (bf16_t)acc[i][j][r];
        if (sel < 2)
          Cn[(size_t)row * DMODEL + col] = v;
        else
          Vo[(size_t)col * S_LEN + row] = v;
      }
}

// Final GEMM: C(fp32) = A(bf16) @ WoB(bf16)^T. r10-validated 128x64/BK=32.
__global__ __launch_bounds__(256) void gemm_out(const bf16_t* __restrict__ A,
                                                const bf16_t* __restrict__ B,
                                                float* __restrict__ C,
                                                int M, int N, int Kd) {
  __shared__ __align__(16) bf16_t As[BM * APITCH];
  __shared__ __align__(16) bf16_t Bs[BN * APITCH];

  const int tid  = threadIdx.x;
  const int wid  = tid >> 6;
  const int lane = tid & 63;
  const int lr   = lane & 15;
  const int quad = lane >> 4;
  const int wm = wid >> 1, wn = wid & 1;
  const int m0 = blockIdx.y * BM;
  const int n0 = blockIdx.x * BN;

  const int ar = tid >> 1, ak = (tid & 1) * 16;
  const bf16_t* ag = A + (size_t)(m0 + ar) * Kd + ak;
  const int br = tid >> 2, bk = (tid & 3) * 8;
  const bf16_t* bg = B + (size_t)(n0 + br) * Kd + bk;

  floatx4 acc[4][2];
#pragma unroll
  for (int i = 0; i < 4; ++i)
#pragma unroll
    for (int j = 0; j < 2; ++j) acc[i][j] = floatx4{0.f, 0.f, 0.f, 0.f};

  bf16x8 pa0 = *(const bf16x8*)(ag);
  bf16x8 pa1 = *(const bf16x8*)(ag + 8);
  bf16x8 pb  = *(const bf16x8*)(bg);

  for (int kb = 0; kb < Kd; kb += BK) {
    __syncthreads();
    *(bf16x8*)(As + ar * APITCH + ak)     = pa0;
    *(bf16x8*)(As + ar * APITCH + ak + 8) = pa1;
    *(bf16x8*)(Bs + br * APITCH + bk)     = pb;
    __syncthreads();

    if (kb + BK < Kd) {
      pa0 = *(const bf16x8*)(ag + kb + BK);
      pa1 = *(const bf16x8*)(ag + kb + BK + 8);
      pb  = *(const bf16x8*)(bg + kb + BK);
    }

    bf16x8 af[4], bfr[2];
#pragma unroll
    for (int i = 0; i < 4; ++i)
      af[i] = *(const bf16x8*)(As + (wm * 64 + i * 16 + lr) * APITCH + quad * 8);
#pragma unroll
    for (int j = 0; j < 2; ++j)
      bfr[j] = *(const bf16x8*)(Bs + (wn * 32 + j * 16 + lr) * APITCH + quad * 8);

#pragma unroll
    for (int i = 0; i < 4; ++i)
#pragma unroll
      for (int j = 0; j < 2; ++j)
        acc[i][j] = mfma16(af[i], bfr[j], acc[i][j]);
  }

#pragma unroll
  for (int i = 0; i < 4; ++i)
#pragma unroll
    for (int j = 0; j < 2; ++j)
#pragma unroll
      for (int r = 0; r < 4; ++r) {
        int row = m0 + wm * 64 + i * 16 + quad * 4 + r;
        int col = n0 + wn * 32 + j * 16 + lr;
        C[(size_t)row * N + col] = acc[i][j][r];
      }
}

// In-place RoPE on Q and K. Q output pre-scaled by SCALE_LOG2E (r13-validated).
__global__ __launch_bounds__(256) void rope_kernel(bf16_t* __restrict__ Q,
                                                   bf16_t* __restrict__ K,
                                                   const void* __restrict__ posv) {
  int idx = blockIdx.x * blockDim.x + threadIdx.x;
  if (idx >= S_LEN * 512) return;
  int s   = idx >> 9;
  int rem = idx & 511;
  int h   = rem >> 5;
  int j   = rem & 31;
  size_t off = (size_t)s * DMODEL + h * DK + 2 * j;

  const long long* p64 = (const long long*)posv;
  const int*       p32 = (const int*)posv;
  unsigned long long w0 = (unsigned long long)p64[0];
  unsigned long long w1 = (unsigned long long)p64[1];
  bool is64 = ((w0 >> 32) == 0ull) && ((w1 >> 32) == 0ull);
  int safe_idx = is64 ? s : 0;
  long long v64 = p64[safe_idx];
  float p = is64 ? (float)v64 : (float)p32[s];

  float inv_freq = expf(-(float)j * (9.210340371976184f / 32.0f));
  float ang = p * inv_freq;
  float sn, cs;
  sincosf(ang, &sn, &cs);

  float q1 = (float)Q[off], q2 = (float)Q[off + 1];
  float csq = cs * SCALE_LOG2E, snq = sn * SCALE_LOG2E;
  Q[off]     = (bf16_t)(q1 * csq - q2 * snq);
  Q[off + 1] = (bf16_t)(q1 * snq + q2 * csq);

  float k1 = (float)K[off], k2 = (float)K[off + 1];
  K[off]     = (bf16_t)(k1 * cs - k2 * sn);
  K[off + 1] = (bf16_t)(k1 * sn + k2 * cs);
}

// Flash attention, r22: DUAL-TILE WAVES — the r21 phase pair (tile A=63-pid,
// tile B=pid) is FUSED into one loop. Each wave owns 16 q-rows of A AND 16
// of B; both are computed against the SAME staged chunk. Since
// maxcA = 64-pid > maxcB = pid+1 always, B's chunks are a prefix of A's:
// B rides A's staging AND A's K/V fragment reads for free. This halves the
// DS-read total (the r21 bottleneck: DS pipe ~65% busy), while keeping every
// block at exactly 65 chunk-computes (uniform, no balance code).
//   - per iteration: stage chunks {2i, 2i+1} (geometry unchanged from r21);
//     per chunk: 8 kf reads + 8 V reads serve up to 4 x 16-row computes.
//   - per-tile compute path (swapped QK, exp2, pack, permlane transpose,
//     mask) is the r21-validated code, macro-ized.
//   - raw lgkm-only barriers (T3/T4) + setprio (T5) kept.
__global__ __launch_bounds__(256, 2) void attn_kernel(const bf16_t* __restrict__ Q,
                                                      const bf16_t* __restrict__ Kb,
                                                      const bf16_t* __restrict__ Vt,
                                                      bf16_t* __restrict__ O) {
  // [0,16384): slot0 {K 8K | V 8K}, [16384,32768): slot1
  __shared__ __align__(16) unsigned char smem[32768];

  const int tid  = threadIdx.x;
  const int wid  = tid >> 6;
  const int lane = tid & 63;
  const int lr   = lane & 15;
  const int quad = lane >> 4;

  const int bid = blockIdx.x;
  const int h   = bid & 15;
  const int pid = bid >> 4;    // 0..31

  const int pA = 63 - pid, pB = pid;
  const int maxcA = pA + 1;            // 33..64
  const int maxcB = pB + 1;            // 1..32
  const int nit   = (maxcA + 1) >> 1;
  const int q0A   = pA * 64 + wid * 16;
  const int q0B   = pB * 64 + wid * 16;

  const bf16_t* Kh = Kb + h * DK;
  const bf16_t* Vh = Vt + (size_t)h * DK * S_LEN;

  // Staging geometry: thread t covers bytes [(t&7)*16, +16) of rows t>>3 and
  // (t>>3)+32 of each 64x128B chunk image. 8 fully-used lines per wave-instr.
  const int r0  = tid >> 3;                 // 0..31
  const int ke  = (tid & 7) * 8;            // element offset in row
  const int ls0 = (r0 * 128 + (tid & 7) * 16) ^ ((r0 & 7) << 4);
  const int ls1 = ls0 + 4096;               // row r0+32 (same &7 -> same swz)
  const int sw  = (lr & 7) << 4;            // frag-read swizzle

  // Q fragments for both tiles (lane holds Q[q0+lr][quad*8..], B-operand of
  // the swapped QK)
  bf16x8 qfA0, qfA1, qfB0, qfB1;
  {
    const bf16_t* Qp = Q + (size_t)(q0A + lr) * DMODEL + h * DK + quad * 8;
    qfA0 = *(const bf16x8*)(Qp);
    qfA1 = *(const bf16x8*)(Qp + 32);
    const bf16_t* Qq = Q + (size_t)(q0B + lr) * DMODEL + h * DK + quad * 8;
    qfB0 = *(const bf16x8*)(Qq);
    qfB1 = *(const bf16x8*)(Qq + 32);
  }

  floatx4 oA[4], oB[4];
#pragma unroll
  for (int dt = 0; dt < 4; ++dt) {
    oA[dt] = floatx4{0.f, 0.f, 0.f, 0.f};
    oB[dt] = floatx4{0.f, 0.f, 0.f, 0.f};
  }
  float lsumA = 0.f, lsumB = 0.f;

  bf16x8 kr[2][2], vr[2][2];
  // prologue: chunks {0,1} (maxcA >= 33, both valid)
#pragma unroll
  for (int j = 0; j < 2; ++j) {
    const bf16_t* kg = Kh + (size_t)(j * 64 + r0) * DMODEL + ke;
    const bf16_t* vg = Vh + (size_t)r0 * S_LEN + j * 64 + ke;
    kr[j][0] = *(const bf16x8*)(kg);
    kr[j][1] = *(const bf16x8*)(kg + (size_t)32 * DMODEL);
    vr[j][0] = *(const bf16x8*)(vg);
    vr[j][1] = *(const bf16x8*)(vg + (size_t)32 * S_LEN);
  }

  for (int i = 0; i < nit; ++i) {
    barrier_lgkm();   // A: ring slots free (no vmcnt drain)
#pragma unroll
    for (int j = 0; j < 2; ++j) {
      unsigned char* Kd = smem + j * 16384;
      *(bf16x8*)(Kd + ls0)        = kr[j][0];
      *(bf16x8*)(Kd + ls1)        = kr[j][1];
      *(bf16x8*)(Kd + 8192 + ls0) = vr[j][0];
      *(bf16x8*)(Kd + 8192 + ls1) = vr[j][1];
    }
    {  // issue next-pair loads; stay in flight across barrier B, land
       // under this iteration's compute (reg-dep wait at next ds_write).
      int cn0 = 2 * i + 2; if (cn0 > maxcA - 1) cn0 = maxcA - 1;
      int cn1 = 2 * i + 3; if (cn1 > maxcA - 1) cn1 = maxcA - 1;
      const int cs0[2] = {cn0, cn1};
#pragma unroll
      for (int j = 0; j < 2; ++j) {
        const bf16_t* kg = Kh + (size_t)(cs0[j] * 64 + r0) * DMODEL + ke;
        const bf16_t* vg = Vh + (size_t)r0 * S_LEN + cs0[j] * 64 + ke;
        kr[j][0] = *(const bf16x8*)(kg);
        kr[j][1] = *(const bf16x8*)(kg + (size_t)32 * DMODEL);
        vr[j][0] = *(const bf16x8*)(vg);
        vr[j][1] = *(const bf16x8*)(vg + (size_t)32 * S_LEN);
      }
    }
    barrier_lgkm();   // B: ring staged (lgkm only; vmcnt in flight)

#pragma unroll
    for (int j = 0; j < 2; ++j) {
      const int c = 2 * i + j;
      if (c < maxcA) {
        const int kvb = c * 64;
        unsigned char* Kbuf = smem + j * 16384;
        unsigned char* Vbuf = Kbuf + 8192;

        bf16x8 kf[4][2];
#pragma unroll
        for (int f = 0; f < 4; ++f) {
          const int rowb = (f * 16 + lr) * 128;
          kf[f][0] = *(const bf16x8*)(Kbuf + rowb + ((quad * 16) ^ sw));
          kf[f][1] = *(const bf16x8*)(Kbuf + rowb + ((quad * 16 + 64) ^ sw));
        }

        bf16x8 pfA0, pfA1;
        QK_SOFTMAX(qfA0, qfA1, lsumA, pfA0, pfA1, q0A, (c == maxcA - 1));

        const bool doB = (c < maxcB);
        bf16x8 pfB0, pfB1;
        if (doB) {
          QK_SOFTMAX(qfB0, qfB1, lsumB, pfB0, pfB1, q0B, (c == maxcB - 1));
        }

        __builtin_amdgcn_s_setprio(1);
        if (doB) {
#pragma unroll
          for (int dt = 0; dt < 4; ++dt) {
            const int rowb = (dt * 16 + lr) * 128;
            bf16x8 v0 = *(const bf16x8*)(Vbuf + rowb + ((quad * 16) ^ sw));
            bf16x8 v1 = *(const bf16x8*)(Vbuf + rowb + ((quad * 16 + 64) ^ sw));
            oA[dt] = mfma16(pfA0, v0, oA[dt]);
            oA[dt] = mfma16(pfA1, v1, oA[dt]);
            oB[dt] = mfma16(pfB0, v0, oB[dt]);
            oB[dt] = mfma16(pfB1, v1, oB[dt]);
          }
        } else {
#pragma unroll
          for (int dt = 0; dt < 4; ++dt) {
            const int rowb = (dt * 16 + lr) * 128;
            bf16x8 v0 = *(const bf16x8*)(Vbuf + rowb + ((quad * 16) ^ sw));
            bf16x8 v1 = *(const bf16x8*)(Vbuf + rowb + ((quad * 16 + 64) ^ sw));
            oA[dt] = mfma16(pfA0, v0, oA[dt]);
            oA[dt] = mfma16(pfA1, v1, oA[dt]);
          }
        }
        __builtin_amdgcn_s_setprio(0);
      }
    }
  }

  // lane-local lsum totals: reduce across quads (lanes lr,lr+16,lr+32,lr+48)
  lsumA += __shfl_xor(lsumA, 16, 64);
  lsumA += __shfl_xor(lsumA, 32, 64);
  lsumB += __shfl_xor(lsumB, 16, 64);
  lsumB += __shfl_xor(lsumB, 32, 64);

  // PV output rows are q0+quad*4+r; that row's lsum lives in lane quad*4+r.
  float invA[4], invB[4];
#pragma unroll
  for (int r = 0; r < 4; ++r) {
    invA[r] = 1.0f / __shfl(lsumA, quad * 4 + r, 64);
    invB[r] = 1.0f / __shfl(lsumB, quad * 4 + r, 64);
  }

  // direct O writes: wave owns rows q0A..+15 and q0B..+15 completely
#pragma unroll
  for (int dt = 0; dt < 4; ++dt)
#pragma unroll
    for (int r = 0; r < 4; ++r) {
      int rowA = q0A + quad * 4 + r;
      O[(size_t)rowA * DMODEL + h * DK + dt * 16 + lr] =
          (bf16_t)(oA[dt][r] * invA[r]);
      int rowB = q0B + quad * 4 + r;
      O[(size_t)rowB * DMODEL + h * DK + dt * 16 + lr] =
          (bf16_t)(oB[dt][r] * invB[r]);
    }
}

extern "C" void kernel_launch(void* const* d_in, const int* in_sizes, int n_in,
                              void* d_out, int out_size, void* d_ws, size_t ws_size,
                              hipStream_t stream) {
  const float* x  = (const float*)d_in[0];
  const float* Wq = (const float*)d_in[1];
  const float* Wk = (const float*)d_in[2];
  const float* Wv = (const float*)d_in[3];
  const float* Wo = (const float*)d_in[4];
  const void* pos = d_in[5];
  float* out = (float*)d_out;

  const size_t NELEM = (size_t)S_LEN * DMODEL;  // 4M elems

  // ws: 32 MB. d_out doubles as bf16 weight scratch until gemm_out.
  bf16_t* xb  = (bf16_t*)d_ws;   // 8 MB (later Ob)
  bf16_t* Qb  = xb + NELEM;      // 8 MB (later WoB)
  bf16_t* Kb  = Qb + NELEM;      // 8 MB
  bf16_t* Vt  = Kb + NELEM;      // 8 MB
  bf16_t* Ob  = xb;
  bf16_t* WB  = (bf16_t*)d_out;  // [WqB|WkB|WvB] bf16, 6 MB of the 16 MB buffer
  bf16_t* WoB = Qb;              // Wo bf16 in Qb region (free after attn)

  dim3 blk(256);

  wcvt3<<<dim3(WELEM / 2048, 3), blk, 0, stream>>>(Wq, Wk, Wv, WB);
  cvt_f32_bf16<<<(int)(NELEM / 8 / 256), blk, 0, stream>>>(x, xb, (int)NELEM);

  // 24 x 32 = 768 blocks (3/CU)
  dim3 gq(3 * DMODEL / QBN, S_LEN / QBM);
  qkv_gemm<<<gq, blk, 0, stream>>>(xb, WB, Qb, Kb, Vt);

  int npairs = S_LEN * 512;
  rope_kernel<<<(npairs + 255) / 256, blk, 0, stream>>>(Qb, Kb, pos);

  // 16 h x 32 dual-tile blocks (tiles 63-pid AND pid fused), 512 uniform
  // blocks (65 chunk-computes each), 2/CU
  attn_kernel<<<NH * 32, blk, 0, stream>>>(Qb, Kb, Vt, Ob);

  wcvt3<<<dim3(WELEM / 2048, 1), blk, 0, stream>>>(Wo, Wo, Wo, WoB);

  dim3 gg(DMODEL / BN, S_LEN / BM);  // (16, 32)
  gemm_out<<<gg, blk, 0, stream>>>(Ob, WoB, out, S_LEN, DMODEL, DMODEL);
}

// Round 7
// 220.929 us; speedup vs baseline: 1.0625x; 1.0625x over previous
//
#include <hip/hip_runtime.h>
#include <hip/hip_bf16.h>
#include <math.h>

typedef __bf16 bf16_t;
typedef __bf16 bf16x8 __attribute__((ext_vector_type(8)));
typedef float floatx4 __attribute__((ext_vector_type(4)));
typedef unsigned int uintx4 __attribute__((ext_vector_type(4)));

#define S_LEN 4096
#define DMODEL 1024
#define NH 16
#define DK 64
#define WELEM (DMODEL * DMODEL)
// 0.125 (1/sqrt(dk)) * log2(e): folded into RoPE's Q output (r13-validated)
#define SCALE_LOG2E 0.1803368801111204f

// qkv GEMM tile (r23): 128x128, BK=32, gll 3-slot ring
#define QBM 128
#define QBN 128
// gemm_out tile (r23): 128x64, BK=32, gll 3-slot ring
#define BM 128
#define BN 64

static __device__ __forceinline__ floatx4 mfma16(bf16x8 a, bf16x8 b, floatx4 c) {
  return __builtin_amdgcn_mfma_f32_16x16x32_bf16(a, b, c, 0, 0, 0);
}

// Raw barrier with lgkm-only wait (attn): NO vmcnt drain.
static __device__ __forceinline__ void barrier_lgkm() {
  __builtin_amdgcn_sched_barrier(0);
  __asm__ volatile("s_waitcnt lgkmcnt(0)" ::: "memory");
  __builtin_amdgcn_s_barrier();
  __builtin_amdgcn_sched_barrier(0);
}

// Counted-vmcnt barrier (GEMMs): wait my oldest staging loads, then sync.
#define VMCNT_BARRIER(N)                                         \
  do {                                                           \
    __builtin_amdgcn_sched_barrier(0);                           \
    __asm__ volatile("s_waitcnt vmcnt(" #N ")" ::: "memory");    \
    __builtin_amdgcn_s_barrier();                                \
    __builtin_amdgcn_sched_barrier(0);                           \
  } while (0)

// global -> LDS direct 16B/lane (wave-uniform LDS base; HW adds lane*16).
typedef __attribute__((address_space(3))) unsigned int lds_u32_t;
typedef __attribute__((address_space(1))) const unsigned int glb_u32_t;
static __device__ __forceinline__ void gll16(const void* g, void* l) {
  __builtin_amdgcn_global_load_lds((glb_u32_t*)g, (lds_u32_t*)l, 16, 0, 0);
}

// bf16 pair pack (truncation — same rounding as the validated >>16 path).
static __device__ __forceinline__ unsigned int packbf(float a, float b) {
  return (__float_as_uint(a) >> 16) | (__float_as_uint(b) & 0xffff0000u);
}

// Paired cross-quad word exchanges (gfx950 permlane*_swap).
static __device__ __forceinline__ void swap32(unsigned int& a, unsigned int& b) {
  auto r = __builtin_amdgcn_permlane32_swap(a, b, false, false);
  a = r[0]; b = r[1];
}
static __device__ __forceinline__ void swap16(unsigned int& a, unsigned int& b) {
  auto r = __builtin_amdgcn_permlane16_swap(a, b, false, false);
  a = r[0]; b = r[1];
}

// Per-tile chunk compute (r21-validated): swapped QK, exp2, causal mask,
// lane-local lsum, bf16 pack + 4x4 cross-quad permlane transpose.
#define QK_SOFTMAX(QF0, QF1, LSUM, PF0, PF1, Q0, MASKED)                     \
  {                                                                          \
    floatx4 s_[4];                                                           \
    __builtin_amdgcn_s_setprio(1);                                           \
    _Pragma("unroll")                                                        \
    for (int f_ = 0; f_ < 4; ++f_) {                                         \
      floatx4 z_ = {0.f, 0.f, 0.f, 0.f};                                     \
      z_ = mfma16(kf[f_][0], QF0, z_);                                       \
      s_[f_] = mfma16(kf[f_][1], QF1, z_);                                   \
    }                                                                        \
    __builtin_amdgcn_s_setprio(0);                                           \
    unsigned int w_[4][2];                                                   \
    _Pragma("unroll")                                                        \
    for (int f_ = 0; f_ < 4; ++f_) {                                         \
      float pe_[4];                                                          \
      _Pragma("unroll")                                                      \
      for (int r_ = 0; r_ < 4; ++r_) {                                       \
        float v_ = __builtin_amdgcn_exp2f(s_[f_][r_]);                       \
        if (MASKED) {                                                        \
          int kv_ = kvb + f_ * 16 + quad * 4 + r_;                           \
          v_ = (kv_ <= (Q0) + lr) ? v_ : 0.f;                                \
        }                                                                    \
        LSUM += v_;                                                          \
        pe_[r_] = v_;                                                        \
      }                                                                      \
      w_[f_][0] = packbf(pe_[0], pe_[1]);                                    \
      w_[f_][1] = packbf(pe_[2], pe_[3]);                                    \
    }                                                                        \
    swap32(w_[0][0], w_[1][0]); swap16(w_[0][0], w_[1][0]);                  \
    swap32(w_[0][1], w_[1][1]); swap16(w_[0][1], w_[1][1]);                  \
    swap32(w_[2][0], w_[3][0]); swap16(w_[2][0], w_[3][0]);                  \
    swap32(w_[2][1], w_[3][1]); swap16(w_[2][1], w_[3][1]);                  \
    uintx4 u0_ = {w_[0][0], w_[0][1], w_[1][0], w_[1][1]};                   \
    uintx4 u1_ = {w_[2][0], w_[2][1], w_[3][0], w_[3][1]};                   \
    __builtin_memcpy(&PF0, &u0_, 16);                                        \
    __builtin_memcpy(&PF1, &u1_, 16);                                        \
  }

// fp32 -> bf16 elementwise convert (n multiple of 8).
__global__ __launch_bounds__(256) void cvt_f32_bf16(const float* __restrict__ src,
                                                    bf16_t* __restrict__ dst, int n) {
  int i = (blockIdx.x * blockDim.x + threadIdx.x) * 8;
  if (i >= n) return;
  float4 a = *(const float4*)(src + i);
  float4 b = *(const float4*)(src + i + 4);
  bf16x8 v;
  v[0] = (bf16_t)a.x; v[1] = (bf16_t)a.y; v[2] = (bf16_t)a.z; v[3] = (bf16_t)a.w;
  v[4] = (bf16_t)b.x; v[5] = (bf16_t)b.y; v[6] = (bf16_t)b.z; v[7] = (bf16_t)b.w;
  *(bf16x8*)(dst + i) = v;
}

// Convert Wq/Wk/Wv (fp32, 1M elems each) -> bf16 at dst[sel*WELEM].
__global__ __launch_bounds__(256) void wcvt3(const float* __restrict__ Wq,
                                             const float* __restrict__ Wk,
                                             const float* __restrict__ Wv,
                                             bf16_t* __restrict__ dst) {
  const int sel = blockIdx.y;
  const float* src = (sel == 0) ? Wq : ((sel == 1) ? Wk : Wv);
  int i = (blockIdx.x * blockDim.x + threadIdx.x) * 8;
  float4 a = *(const float4*)(src + i);
  float4 b = *(const float4*)(src + i + 4);
  bf16x8 v;
  v[0] = (bf16_t)a.x; v[1] = (bf16_t)a.y; v[2] = (bf16_t)a.z; v[3] = (bf16_t)a.w;
  v[4] = (bf16_t)b.x; v[5] = (bf16_t)b.y; v[6] = (bf16_t)b.z; v[7] = (bf16_t)b.w;
  *(bf16x8*)(dst + (size_t)sel * WELEM + i) = v;
}

// FUSED QKV GEMM, r23: global_load_lds staging (width 16), linear 64B-row LDS
// with XOR swizzle (pre-swizzled global source + swizzled frag reads — rule
// "both-sides-or-neither"), 3-slot ring, ONE raw barrier + counted vmcnt(4)
// per iteration (prefetch depth = 2 K-steps). BK=32, NIT=32. 48KB LDS ->
// 3 blocks/CU (grid 768 = exactly 3/CU). Epilogue/acc layout unchanged.
__global__ __launch_bounds__(256, 3) void qkv_gemm(const bf16_t* __restrict__ A,
                                                   const bf16_t* __restrict__ WB,
                                                   bf16_t* __restrict__ Qo,
                                                   bf16_t* __restrict__ Ko,
                                                   bf16_t* __restrict__ Vo) {
  // 3 slots x {A[128][64B] | B[128][64B]} = 3 x 16 KB
  __shared__ __align__(16) unsigned char smem[49152];

  const int tid  = threadIdx.x;
  const int wid  = tid >> 6;
  const int lane = tid & 63;
  const int lr   = lane & 15;
  const int quad = lane >> 4;
  const int wm = wid >> 1, wn = wid & 1;
  const int sel = blockIdx.x >> 3;              // 0=Q, 1=K, 2=V
  const int n0  = (blockIdx.x & 7) * QBN;
  const int m0  = blockIdx.y * QBM;
  const bf16_t* Bsrc = WB + (size_t)sel * WELEM;

  // Staging: wave w stages {w<2: A rows w*64.., w>=2: B rows (w&1)*64..},
  // 4 gll per thread per K-step (each = 16 rows x 64B). Lane l covers row
  // l>>2, col-bytes (l&3)*16 of the LDS image; global source col is
  // pre-swizzled by ((row&3)<<4) so frag reads XOR the same.
  const int mat  = wid >> 1;                 // 0=A, 1=B
  const int lrow = lane >> 2;                // 0..15
  const int swzl = ((lane & 3) * 16) ^ ((lrow & 3) << 4);
  const unsigned char* gbase =
      (const unsigned char*)(mat ? Bsrc : A) +
      (size_t)((mat ? n0 : m0) + (wid & 1) * 64 + lrow) * (DMODEL * 2) + swzl;
  const int lds_w = mat * 8192 + (wid & 1) * 4096;  // + k*1024 + slot*16384

  floatx4 acc[4][4];
#pragma unroll
  for (int i = 0; i < 4; ++i)
#pragma unroll
    for (int j = 0; j < 4; ++j) acc[i][j] = floatx4{0.f, 0.f, 0.f, 0.f};

  // prologue: K-steps 0,1 into slots 0,1
#pragma unroll
  for (int st = 0; st < 2; ++st) {
    const unsigned char* gs = gbase + st * 64;
    unsigned char* ls = smem + st * 16384 + lds_w;
#pragma unroll
    for (int k = 0; k < 4; ++k)
      gll16(gs + (size_t)k * (16 * 2048), ls + k * 1024);
  }

  const int frsw = 16 * (quad ^ (lr & 3));
  int csl = 0, isl = 2;
  for (int it = 0; it < 32; ++it) {
    VMCNT_BARRIER(4);   // my step-it loads landed; barrier -> everyone's

    {  // issue step it+2 into slot isl (freed by the barrier above).
       // Dummy-clamped data for it+2>=32 keeps vmcnt accounting constant.
      int sd = it + 2; if (sd > 31) sd = 31;
      const unsigned char* gs = gbase + sd * 64;
      unsigned char* ls = smem + isl * 16384 + lds_w;
#pragma unroll
      for (int k = 0; k < 4; ++k)
        gll16(gs + (size_t)k * (16 * 2048), ls + k * 1024);
    }

    const unsigned char* As_ = smem + csl * 16384;
    bf16x8 af[4], bfr[4];
#pragma unroll
    for (int i = 0; i < 4; ++i)
      af[i] = *(const bf16x8*)(As_ + (wm * 64 + i * 16 + lr) * 64 + frsw);
#pragma unroll
    for (int j = 0; j < 4; ++j)
      bfr[j] = *(const bf16x8*)(As_ + 8192 + (wn * 64 + j * 16 + lr) * 64 + frsw);

    __builtin_amdgcn_s_setprio(1);
#pragma unroll
    for (int i = 0; i < 4; ++i)
#pragma unroll
      for (int j = 0; j < 4; ++j)
        acc[i][j] = mfma16(af[i], bfr[j], acc[i][j]);
    __builtin_amdgcn_s_setprio(0);

    csl = (csl == 2) ? 0 : csl + 1;
    isl = (isl == 2) ? 0 : isl + 1;
  }

  bf16_t* Cn = (sel == 0) ? Qo : Ko;
#pragma unroll
  for (int i = 0; i < 4; ++i)
#pragma unroll
    for (int j = 0; j < 4; ++j)
#pragma unroll
      for (int r = 0; r < 4; ++r) {
        int row = m0 + wm * 64 + i * 16 + quad * 4 + r;
        int col = n0 + wn * 64 + j * 16 + lr;
        bf16_t v = (bf16_t)acc[i][j][r];
        if (sel < 2)
          Cn[(size_t)row * DMODEL + col] = v;
        else
          Vo[(size_t)col * S_LEN + row] = v;
      }
}

// Final GEMM, r23: same gll + 3-slot-ring + counted vmcnt(3) structure.
// Tile 128x64, BK=32. Slot = A 8KB + B 4KB = 12KB; ring 36KB.
__global__ __launch_bounds__(256, 2) void gemm_out(const bf16_t* __restrict__ A,
                                                   const bf16_t* __restrict__ B,
                                                   float* __restrict__ C,
                                                   int M, int N, int Kd) {
  __shared__ __align__(16) unsigned char smem[36864];

  const int tid  = threadIdx.x;
  const int wid  = tid >> 6;
  const int lane = tid & 63;
  const int lr   = lane & 15;
  const int quad = lane >> 4;
  const int wm = wid >> 1, wn = wid & 1;
  const int m0 = blockIdx.y * BM;
  const int n0 = blockIdx.x * BN;
  const int NIT = Kd >> 5;                 // 32

  // Staging: 12 wave-instrs (1KB each): ids 0..7 = A rows id*16..,
  // ids 8..11 = B rows (id-8)*16.. ; wave w handles ids w*3..w*3+2.
  const int lrow = lane >> 2;
  const int swzl = ((lane & 3) * 16) ^ ((lrow & 3) << 4);
  const unsigned char* gk[3];
  int lo[3];
#pragma unroll
  for (int k = 0; k < 3; ++k) {
    int id = wid * 3 + k;
    bool mb = id >= 8;
    int r = (id - (mb ? 8 : 0)) * 16 + lrow;
    gk[k] = (const unsigned char*)(mb ? B : A) +
            (size_t)((mb ? n0 : m0) + r) * ((size_t)Kd * 2) + swzl;
    lo[k] = mb ? (8192 + (id - 8) * 1024) : (id * 1024);
  }

  floatx4 acc[4][2];
#pragma unroll
  for (int i = 0; i < 4; ++i)
#pragma unroll
    for (int j = 0; j < 2; ++j) acc[i][j] = floatx4{0.f, 0.f, 0.f, 0.f};

#pragma unroll
  for (int st = 0; st < 2; ++st) {
    unsigned char* ls = smem + st * 12288;
#pragma unroll
    for (int k = 0; k < 3; ++k)
      gll16(gk[k] + st * 64, ls + lo[k]);
  }

  const int frsw = 16 * (quad ^ (lr & 3));
  int csl = 0, isl = 2;
  for (int it = 0; it < NIT; ++it) {
    VMCNT_BARRIER(3);

    {
      int sd = it + 2; if (sd > NIT - 1) sd = NIT - 1;
      unsigned char* ls = smem + isl * 12288;
#pragma unroll
      for (int k = 0; k < 3; ++k)
        gll16(gk[k] + sd * 64, ls + lo[k]);
    }

    const unsigned char* As_ = smem + csl * 12288;
    bf16x8 af[4], bfr[2];
#pragma unroll
    for (int i = 0; i < 4; ++i)
      af[i] = *(const bf16x8*)(As_ + (wm * 64 + i * 16 + lr) * 64 + frsw);
#pragma unroll
    for (int j = 0; j < 2; ++j)
      bfr[j] = *(const bf16x8*)(As_ + 8192 + (wn * 32 + j * 16 + lr) * 64 + frsw);

    __builtin_amdgcn_s_setprio(1);
#pragma unroll
    for (int i = 0; i < 4; ++i)
#pragma unroll
      for (int j = 0; j < 2; ++j)
        acc[i][j] = mfma16(af[i], bfr[j], acc[i][j]);
    __builtin_amdgcn_s_setprio(0);

    csl = (csl == 2) ? 0 : csl + 1;
    isl = (isl == 2) ? 0 : isl + 1;
  }

#pragma unroll
  for (int i = 0; i < 4; ++i)
#pragma unroll
    for (int j = 0; j < 2; ++j)
#pragma unroll
      for (int r = 0; r < 4; ++r) {
        int row = m0 + wm * 64 + i * 16 + quad * 4 + r;
        int col = n0 + wn * 32 + j * 16 + lr;
        C[(size_t)row * N + col] = acc[i][j][r];
      }
}

// In-place RoPE on Q and K. Q output pre-scaled by SCALE_LOG2E (r13-validated).
__global__ __launch_bounds__(256) void rope_kernel(bf16_t* __restrict__ Q,
                                                   bf16_t* __restrict__ K,
                                                   const void* __restrict__ posv) {
  int idx = blockIdx.x * blockDim.x + threadIdx.x;
  if (idx >= S_LEN * 512) return;
  int s   = idx >> 9;
  int rem = idx & 511;
  int h   = rem >> 5;
  int j   = rem & 31;
  size_t off = (size_t)s * DMODEL + h * DK + 2 * j;

  const long long* p64 = (const long long*)posv;
  const int*       p32 = (const int*)posv;
  unsigned long long w0 = (unsigned long long)p64[0];
  unsigned long long w1 = (unsigned long long)p64[1];
  bool is64 = ((w0 >> 32) == 0ull) && ((w1 >> 32) == 0ull);
  int safe_idx = is64 ? s : 0;
  long long v64 = p64[safe_idx];
  float p = is64 ? (float)v64 : (float)p32[s];

  float inv_freq = expf(-(float)j * (9.210340371976184f / 32.0f));
  float ang = p * inv_freq;
  float sn, cs;
  sincosf(ang, &sn, &cs);

  float q1 = (float)Q[off], q2 = (float)Q[off + 1];
  float csq = cs * SCALE_LOG2E, snq = sn * SCALE_LOG2E;
  Q[off]     = (bf16_t)(q1 * csq - q2 * snq);
  Q[off + 1] = (bf16_t)(q1 * snq + q2 * csq);

  float k1 = (float)K[off], k2 = (float)K[off + 1];
  K[off]     = (bf16_t)(k1 * cs - k2 * sn);
  K[off + 1] = (bf16_t)(k1 * sn + k2 * cs);
}

// Flash attention, r22 structure (UNCHANGED, validated 76us): dual-tile waves,
// in-register P transpose, raw lgkm barriers, reg-prefetch staging.
__global__ __launch_bounds__(256, 2) void attn_kernel(const bf16_t* __restrict__ Q,
                                                      const bf16_t* __restrict__ Kb,
                                                      const bf16_t* __restrict__ Vt,
                                                      bf16_t* __restrict__ O) {
  __shared__ __align__(16) unsigned char smem[32768];

  const int tid  = threadIdx.x;
  const int wid  = tid >> 6;
  const int lane = tid & 63;
  const int lr   = lane & 15;
  const int quad = lane >> 4;

  const int bid = blockIdx.x;
  const int h   = bid & 15;
  const int pid = bid >> 4;    // 0..31

  const int pA = 63 - pid, pB = pid;
  const int maxcA = pA + 1;
  const int maxcB = pB + 1;
  const int nit   = (maxcA + 1) >> 1;
  const int q0A   = pA * 64 + wid * 16;
  const int q0B   = pB * 64 + wid * 16;

  const bf16_t* Kh = Kb + h * DK;
  const bf16_t* Vh = Vt + (size_t)h * DK * S_LEN;

  const int r0  = tid >> 3;
  const int ke  = (tid & 7) * 8;
  const int ls0 = (r0 * 128 + (tid & 7) * 16) ^ ((r0 & 7) << 4);
  const int ls1 = ls0 + 4096;
  const int sw  = (lr & 7) << 4;

  bf16x8 qfA0, qfA1, qfB0, qfB1;
  {
    const bf16_t* Qp = Q + (size_t)(q0A + lr) * DMODEL + h * DK + quad * 8;
    qfA0 = *(const bf16x8*)(Qp);
    qfA1 = *(const bf16x8*)(Qp + 32);
    const bf16_t* Qq = Q + (size_t)(q0B + lr) * DMODEL + h * DK + quad * 8;
    qfB0 = *(const bf16x8*)(Qq);
    qfB1 = *(const bf16x8*)(Qq + 32);
  }

  floatx4 oA[4], oB[4];
#pragma unroll
  for (int dt = 0; dt < 4; ++dt) {
    oA[dt] = floatx4{0.f, 0.f, 0.f, 0.f};
    oB[dt] = floatx4{0.f, 0.f, 0.f, 0.f};
  }
  float lsumA = 0.f, lsumB = 0.f;

  bf16x8 kr[2][2], vr[2][2];
#pragma unroll
  for (int j = 0; j < 2; ++j) {
    const bf16_t* kg = Kh + (size_t)(j * 64 + r0) * DMODEL + ke;
    const bf16_t* vg = Vh + (size_t)r0 * S_LEN + j * 64 + ke;
    kr[j][0] = *(const bf16x8*)(kg);
    kr[j][1] = *(const bf16x8*)(kg + (size_t)32 * DMODEL);
    vr[j][0] = *(const bf16x8*)(vg);
    vr[j][1] = *(const bf16x8*)(vg + (size_t)32 * S_LEN);
  }

  for (int i = 0; i < nit; ++i) {
    barrier_lgkm();
#pragma unroll
    for (int j = 0; j < 2; ++j) {
      unsigned char* Kd = smem + j * 16384;
      *(bf16x8*)(Kd + ls0)        = kr[j][0];
      *(bf16x8*)(Kd + ls1)        = kr[j][1];
      *(bf16x8*)(Kd + 8192 + ls0) = vr[j][0];
      *(bf16x8*)(Kd + 8192 + ls1) = vr[j][1];
    }
    {
      int cn0 = 2 * i + 2; if (cn0 > maxcA - 1) cn0 = maxcA - 1;
      int cn1 = 2 * i + 3; if (cn1 > maxcA - 1) cn1 = maxcA - 1;
      const int cs0[2] = {cn0, cn1};
#pragma unroll
      for (int j = 0; j < 2; ++j) {
        const bf16_t* kg = Kh + (size_t)(cs0[j] * 64 + r0) * DMODEL + ke;
        const bf16_t* vg = Vh + (size_t)r0 * S_LEN + cs0[j] * 64 + ke;
        kr[j][0] = *(const bf16x8*)(kg);
        kr[j][1] = *(const bf16x8*)(kg + (size_t)32 * DMODEL);
        vr[j][0] = *(const bf16x8*)(vg);
        vr[j][1] = *(const bf16x8*)(vg + (size_t)32 * S_LEN);
      }
    }
    barrier_lgkm();

#pragma unroll
    for (int j = 0; j < 2; ++j) {
      const int c = 2 * i + j;
      if (c < maxcA) {
        const int kvb = c * 64;
        unsigned char* Kbuf = smem + j * 16384;
        unsigned char* Vbuf = Kbuf + 8192;

        bf16x8 kf[4][2];
#pragma unroll
        for (int f = 0; f < 4; ++f) {
          const int rowb = (f * 16 + lr) * 128;
          kf[f][0] = *(const bf16x8*)(Kbuf + rowb + ((quad * 16) ^ sw));
          kf[f][1] = *(const bf16x8*)(Kbuf + rowb + ((quad * 16 + 64) ^ sw));
        }

        bf16x8 pfA0, pfA1;
        QK_SOFTMAX(qfA0, qfA1, lsumA, pfA0, pfA1, q0A, (c == maxcA - 1));

        const bool doB = (c < maxcB);
        bf16x8 pfB0, pfB1;
        if (doB) {
          QK_SOFTMAX(qfB0, qfB1, lsumB, pfB0, pfB1, q0B, (c == maxcB - 1));
        }

        __builtin_amdgcn_s_setprio(1);
        if (doB) {
#pragma unroll
          for (int dt = 0; dt < 4; ++dt) {
            const int rowb = (dt * 16 + lr) * 128;
            bf16x8 v0 = *(const bf16x8*)(Vbuf + rowb + ((quad * 16) ^ sw));
            bf16x8 v1 = *(const bf16x8*)(Vbuf + rowb + ((quad * 16 + 64) ^ sw));
            oA[dt] = mfma16(pfA0, v0, oA[dt]);
            oA[dt] = mfma16(pfA1, v1, oA[dt]);
            oB[dt] = mfma16(pfB0, v0, oB[dt]);
            oB[dt] = mfma16(pfB1, v1, oB[dt]);
          }
        } else {
#pragma unroll
          for (int dt = 0; dt < 4; ++dt) {
            const int rowb = (dt * 16 + lr) * 128;
            bf16x8 v0 = *(const bf16x8*)(Vbuf + rowb + ((quad * 16) ^ sw));
            bf16x8 v1 = *(const bf16x8*)(Vbuf + rowb + ((quad * 16 + 64) ^ sw));
            oA[dt] = mfma16(pfA0, v0, oA[dt]);
            oA[dt] = mfma16(pfA1, v1, oA[dt]);
          }
        }
        __builtin_amdgcn_s_setprio(0);
      }
    }
  }

  lsumA += __shfl_xor(lsumA, 16, 64);
  lsumA += __shfl_xor(lsumA, 32, 64);
  lsumB += __shfl_xor(lsumB, 16, 64);
  lsumB += __shfl_xor(lsumB, 32, 64);

  float invA[4], invB[4];
#pragma unroll
  for (int r = 0; r < 4; ++r) {
    invA[r] = 1.0f / __shfl(lsumA, quad * 4 + r, 64);
    invB[r] = 1.0f / __shfl(lsumB, quad * 4 + r, 64);
  }

#pragma unroll
  for (int dt = 0; dt < 4; ++dt)
#pragma unroll
    for (int r = 0; r < 4; ++r) {
      int rowA = q0A + quad * 4 + r;
      O[(size_t)rowA * DMODEL + h * DK + dt * 16 + lr] =
          (bf16_t)(oA[dt][r] * invA[r]);
      int rowB = q0B + quad * 4 + r;
      O[(size_t)rowB * DMODEL + h * DK + dt * 16 + lr] =
          (bf16_t)(oB[dt][r] * invB[r]);
    }
}

extern "C" void kernel_launch(void* const* d_in, const int* in_sizes, int n_in,
                              void* d_out, int out_size, void* d_ws, size_t ws_size,
                              hipStream_t stream) {
  const float* x  = (const float*)d_in[0];
  const float* Wq = (const float*)d_in[1];
  const float* Wk = (const float*)d_in[2];
  const float* Wv = (const float*)d_in[3];
  const float* Wo = (const float*)d_in[4];
  const void* pos = d_in[5];
  float* out = (float*)d_out;

  const size_t NELEM = (size_t)S_LEN * DMODEL;  // 4M elems

  // ws: 32 MB. d_out doubles as bf16 weight scratch until gemm_out.
  bf16_t* xb  = (bf16_t*)d_ws;   // 8 MB (later Ob)
  bf16_t* Qb  = xb + NELEM;      // 8 MB (later WoB)
  bf16_t* Kb  = Qb + NELEM;      // 8 MB
  bf16_t* Vt  = Kb + NELEM;      // 8 MB
  bf16_t* Ob  = xb;
  bf16_t* WB  = (bf16_t*)d_out;  // [WqB|WkB|WvB] bf16, 6 MB of the 16 MB buffer
  bf16_t* WoB = Qb;              // Wo bf16 in Qb region (free after attn)

  dim3 blk(256);

  wcvt3<<<dim3(WELEM / 2048, 3), blk, 0, stream>>>(Wq, Wk, Wv, WB);
  cvt_f32_bf16<<<(int)(NELEM / 8 / 256), blk, 0, stream>>>(x, xb, (int)NELEM);

  // 24 x 32 = 768 blocks (3/CU)
  dim3 gq(3 * DMODEL / QBN, S_LEN / QBM);
  qkv_gemm<<<gq, blk, 0, stream>>>(xb, WB, Qb, Kb, Vt);

  int npairs = S_LEN * 512;
  rope_kernel<<<(npairs + 255) / 256, blk, 0, stream>>>(Qb, Kb, pos);

  // 16 h x 32 dual-tile blocks, 512 uniform blocks, 2/CU
  attn_kernel<<<NH * 32, blk, 0, stream>>>(Qb, Kb, Vt, Ob);

  wcvt3<<<dim3(WELEM / 2048, 1), blk, 0, stream>>>(Wo, Wo, Wo, WoB);

  dim3 gg(DMODEL / BN, S_LEN / BM);  // (16, 32)
  gemm_out<<<gg, blk, 0, stream>>>(Ob, WoB, out, S_LEN, DMODEL, DMODEL);
}